// Round 5
// baseline (381.990 us; speedup 1.0000x reference)
//
#include <hip/hip_runtime.h>

#define N_NODES 50000
#define N_EDGES 800000
#define F 128
#define BF 256
#define NF (N_NODES * F)
#define CAP 64                       // slots per node (max degree here ~40)
#define SPILL_CAP 131072
#define TILE 16
#define AGS 264                      // LDS row stride in halfs: 528B, 16B-aligned

typedef __attribute__((ext_vector_type(8))) _Float16 half8;
typedef __attribute__((ext_vector_type(4))) _Float16 half4;
typedef __attribute__((ext_vector_type(4))) float floatx4;

// ========== scatter: 4-edge batched binning + deg atomics (standalone) ======
// No streaming co-tenant -> slot lines + cnt/deg stay L2-resident.
__global__ __launch_bounds__(256) void k_scatter(const int* __restrict__ ei,
                                                 const float* __restrict__ attr,
                                                 int* __restrict__ cnt,        // [N+1], last = nspill
                                                 float* __restrict__ deg,      // [N]
                                                 uint4* __restrict__ spill,
                                                 unsigned* __restrict__ slots) // [N][CAP] c<<15|q15(a)
{
    int t = blockIdx.x * 256 + threadIdx.x;
    if (t >= 200000) return;                  // 200000 * 4 == N_EDGES
    int e0 = t, e1 = t + 200000, e2 = t + 400000, e3 = t + 600000;
    int   r0 = ei[e0], r1 = ei[e1], r2 = ei[e2], r3 = ei[e3];
    int   c0 = ei[N_EDGES + e0], c1 = ei[N_EDGES + e1];
    int   c2 = ei[N_EDGES + e2], c3 = ei[N_EDGES + e3];
    float a0 = attr[e0], a1 = attr[e1], a2 = attr[e2], a3 = attr[e3];

    atomicAdd(&deg[r0], a0);
    atomicAdd(&deg[r1], a1);
    atomicAdd(&deg[r2], a2);
    atomicAdd(&deg[r3], a3);

    int s0 = atomicAdd(&cnt[r0], 1);
    int s1 = atomicAdd(&cnt[r1], 1);
    int s2 = atomicAdd(&cnt[r2], 1);
    int s3 = atomicAdd(&cnt[r3], 1);

#define STORE_EDGE(R, C, A, S)                                                \
    {                                                                         \
        unsigned q  = (unsigned)((A) * 32767.0f + 0.5f);                      \
        unsigned pk = ((unsigned)(C) << 15) | q;                              \
        if ((S) < CAP) {                                                      \
            slots[(size_t)(R) * CAP + (S)] = pk;                              \
        } else {                                                              \
            int sp = atomicAdd(&cnt[N_NODES], 1);                             \
            if (sp < SPILL_CAP)                                               \
                spill[sp] = make_uint4((unsigned)(R), (unsigned)(C),          \
                                       __float_as_uint(A), 0u);               \
        }                                                                     \
    }
    STORE_EDGE(r0, c0, a0, s0)
    STORE_EDGE(r1, c1, a1, s1)
    STORE_EDGE(r2, c2, a2, s2)
    STORE_EDGE(r3, c3, a3, s3)
#undef STORE_EDGE
}

// ========== prep: pure streaming — x->fp16, W->fp16, dinv=rsqrt(deg+1) ======
__global__ __launch_bounds__(256) void k_prep(const float* __restrict__ x,
                                              const float* __restrict__ W,
                                              float* __restrict__ dinv,   // in-place over deg
                                              _Float16* __restrict__ xi,
                                              _Float16* __restrict__ Wh) {
    int t = blockIdx.x * 256 + threadIdx.x;   // 12500 blocks * 256 == 2*NF/4

    {
        size_t base = (size_t)t * 4;
        int b = (base >= (size_t)NF) ? 1 : 0;
        size_t rem = base - (size_t)b * NF;
        int n = (int)(rem >> 7);
        int f = (int)(rem & 127);
        float4 v = *(const float4*)(x + base);
        half4 h;
        h[0] = (_Float16)v.x; h[1] = (_Float16)v.y;
        h[2] = (_Float16)v.z; h[3] = (_Float16)v.w;
        *(half4*)(xi + (size_t)n * BF + b * F + f) = h;
    }
    if (t < 4096) {
        float4 w = ((const float4*)W)[t];
        half4 h;
        h[0] = (_Float16)w.x; h[1] = (_Float16)w.y;
        h[2] = (_Float16)w.z; h[3] = (_Float16)w.w;
        ((half4*)Wh)[t] = h;
    }
    if (t < N_NODES) dinv[t] = rsqrtf(dinv[t] + 1.0f);   // dinv aliases deg
}

// ---- pair-load neighbor accumulation: one dwordx4 covers TWO edges ---------
// lanes 0..31 handle even edge of the pair, lanes 32..63 the odd edge; each
// lane covers 8 contiguous cols (16B). 8 pairs in flight = 128 cache lines.
#define PAIR_LOAD(U, JP)                                                      \
    int   c##U = __shfl(ec, ((JP) + U) * 2 + hi);                             \
    float q##U = __shfl(pw, ((JP) + U) * 2 + hi);                             \
    half8 v##U = *(const half8*)(xi + (size_t)c##U * BF + off);

#define PAIR_ACC(U)                                                           \
    _Pragma("unroll")                                                         \
    for (int k = 0; k < 8; ++k) acc8[k] += q##U * (float)v##U[k];             \
    sp += q##U;

// ========== fused gather (LDS tile) + MFMA GEMM, pair-loads =================
__global__ __launch_bounds__(256, 8) void k_fused(const int* __restrict__ cnt,
                                                  const unsigned* __restrict__ slots,
                                                  const uint4* __restrict__ spill,
                                                  const _Float16* __restrict__ xi,
                                                  const float* __restrict__ dinv,
                                                  const _Float16* __restrict__ Wh,
                                                  const float* __restrict__ bias,
                                                  float* __restrict__ out) {
    __shared__ _Float16 ag[TILE * AGS];
    __shared__ float ss[TILE];
    const int tid  = threadIdx.x;
    const int wave = tid >> 6, lane = tid & 63;
    const int n0   = blockIdx.x * TILE;           // 3125*16 == 50000 exactly
    const int hi   = lane >> 5;                   // which edge of the pair
    const int off  = (lane & 31) * 8;             // 8 cols (16B) per lane
    const int rbase = n0 + wave * 4;

    int cns[4];
#pragma unroll
    for (int i = 0; i < 4; ++i) cns[i] = cnt[rbase + i];

    // prefetch row 0 meta
    unsigned pk_cur = 0u;
    float    dp_cur = 0.0f;
    {
        int m0 = (cns[0] < CAP) ? cns[0] : CAP;
        if (lane < m0) {
            pk_cur = slots[(size_t)rbase * CAP + lane];
            dp_cur = dinv[pk_cur >> 15];
        }
    }

#pragma unroll
    for (int i = 0; i < 4; ++i) {
        const int rl = wave * 4 + i;
        const int r  = rbase + i;
        const int cn = cns[i];
        const int m  = (cn < CAP) ? cn : CAP;

        int   ec = (int)(pk_cur >> 15);
        float pw = (lane < m) ? (float)(pk_cur & 0x7FFFu) * (1.0f / 32767.0f) * dp_cur : 0.0f;

        // prefetch next row meta; hides under this row's NB loop
        unsigned pk_nxt = 0u;
        float    dp_nxt = 0.0f;
        if (i < 3) {
            int mn = (cns[i + 1] < CAP) ? cns[i + 1] : CAP;
            if (lane < mn) {
                pk_nxt = slots[(size_t)(r + 1) * CAP + lane];
                dp_nxt = dinv[pk_nxt >> 15];
            }
        }

        float dinvr = dinv[r];
        float nm0   = dinvr * dinvr;
        half8 hv    = *(const half8*)(xi + (size_t)r * BF + off);

        float acc8[8];
#pragma unroll
        for (int k = 0; k < 8; ++k) acc8[k] = 0.0f;
        float sp = 0.0f;

        const int P = (m + 1) >> 1;               // pairs (odd m padded w/ pw=0)
        int jp = 0;
        for (; jp + 8 <= P; jp += 8) {
            PAIR_LOAD(0, jp) PAIR_LOAD(1, jp) PAIR_LOAD(2, jp) PAIR_LOAD(3, jp)
            PAIR_LOAD(4, jp) PAIR_LOAD(5, jp) PAIR_LOAD(6, jp) PAIR_LOAD(7, jp)
            PAIR_ACC(0) PAIR_ACC(1) PAIR_ACC(2) PAIR_ACC(3)
            PAIR_ACC(4) PAIR_ACC(5) PAIR_ACC(6) PAIR_ACC(7)
        }
        if (jp + 4 <= P) {
            PAIR_LOAD(0, jp) PAIR_LOAD(1, jp) PAIR_LOAD(2, jp) PAIR_LOAD(3, jp)
            PAIR_ACC(0) PAIR_ACC(1) PAIR_ACC(2) PAIR_ACC(3)
            jp += 4;
        }
        for (; jp < P; ++jp) {
            PAIR_LOAD(0, jp)
            PAIR_ACC(0)
        }

        if (cn > CAP) {
            int ns = cnt[N_NODES]; if (ns > SPILL_CAP) ns = SPILL_CAP;
            for (int k = 0; k < ns; ++k) {
                uint4 e = spill[k];
                if ((int)e.x == r) {
                    int   c = (int)e.y;
                    float p = __uint_as_float(e.z) * dinv[c];
                    float ph = hi ? 0.0f : p;     // count once (half 0 only)
                    half8 v = *(const half8*)(xi + (size_t)c * BF + off);
#pragma unroll
                    for (int k8 = 0; k8 < 8; ++k8) acc8[k8] += ph * (float)v[k8];
                    sp += ph;
                }
            }
        }

        // fold the two half-wave edge subsets
#pragma unroll
        for (int k = 0; k < 8; ++k) acc8[k] += __shfl_xor(acc8[k], 32);
        sp += __shfl_xor(sp, 32);

        if (hi == 0) {
            half8 ho;
#pragma unroll
            for (int k = 0; k < 8; ++k)
                ho[k] = (_Float16)(dinvr * acc8[k] + nm0 * (float)hv[k]);
            *(half8*)&ag[rl * AGS + lane * 8] = ho;   // lane<32: 16B each
        }
        if (lane == 0) ss[rl] = dinvr * sp + nm0;

        pk_cur = pk_nxt;
        dp_cur = dp_nxt;
    }
    __syncthreads();

    // ---- GEMM phase: wave handles output cols [wave*32, wave*32+32) ----
    const int ln = lane & 15, quad = lane >> 4;
    const int obase = wave * 32;
    floatx4 acc00 = (floatx4){0.f,0.f,0.f,0.f}, acc01 = acc00;
    floatx4 acc10 = acc00, acc11 = acc00;

    for (int k0 = 0; k0 < 4; ++k0) {
        half8 a0 = *(const half8*)&ag[ln * AGS + k0 * 32 + quad * 8];        // batch 0
        half8 a1 = *(const half8*)&ag[ln * AGS + 128 + k0 * 32 + quad * 8];  // batch 1
        half8 b0 = *(const half8*)(Wh + (size_t)(obase + ln) * F + k0 * 32 + quad * 8);
        half8 b1 = *(const half8*)(Wh + (size_t)(obase + 16 + ln) * F + k0 * 32 + quad * 8);
        acc00 = __builtin_amdgcn_mfma_f32_16x16x32_f16(a0, b0, acc00, 0, 0, 0);
        acc01 = __builtin_amdgcn_mfma_f32_16x16x32_f16(a0, b1, acc01, 0, 0, 0);
        acc10 = __builtin_amdgcn_mfma_f32_16x16x32_f16(a1, b0, acc10, 0, 0, 0);
        acc11 = __builtin_amdgcn_mfma_f32_16x16x32_f16(a1, b1, acc11, 0, 0, 0);
    }

    float sv[4];
    for (int rg = 0; rg < 4; ++rg) sv[rg] = ss[quad * 4 + rg];
    {
        int o0 = obase + ln, o1 = obase + 16 + ln;
        float bo0 = bias[o0], bo1 = bias[o1];
        for (int rg = 0; rg < 4; ++rg) {
            int n = n0 + quad * 4 + rg;
            out[(size_t)n * F + o0]              = fmaxf(acc00[rg] + sv[rg] * bo0, 0.0f);
            out[(size_t)n * F + o1]              = fmaxf(acc01[rg] + sv[rg] * bo1, 0.0f);
            out[(size_t)NF + (size_t)n * F + o0] = fmaxf(acc10[rg] + sv[rg] * bo0, 0.0f);
            out[(size_t)NF + (size_t)n * F + o1] = fmaxf(acc11[rg] + sv[rg] * bo1, 0.0f);
        }
    }
}

// ========== atomic fallback pieces (tiny ws) ================================
__global__ void k_deg(const int* __restrict__ ei, const float* __restrict__ attr,
                      float* __restrict__ deg) {
    int e = blockIdx.x * 256 + threadIdx.x;
    if (e < N_EDGES) atomicAdd(&deg[ei[e]], attr[e]);
}
__global__ void k_dinv(float* __restrict__ deg) {
    int n = blockIdx.x * 256 + threadIdx.x;
    if (n < N_NODES) deg[n] = rsqrtf(deg[n] + 1.0f);
}
__global__ __launch_bounds__(256) void k_edge(const int* __restrict__ ei,
                                              const float* __restrict__ attr,
                                              const float* __restrict__ dinv,
                                              const float* __restrict__ x,
                                              float* __restrict__ out,
                                              float* __restrict__ s) {
    int e    = (int)(((size_t)blockIdx.x * 256 + threadIdx.x) >> 6);
    int lane = threadIdx.x & 63;
    if (e >= N_EDGES) return;
    int r = ei[e];
    int c = ei[N_EDGES + e];
    float norm = dinv[r] * attr[e] * dinv[c];
    if (lane == 0) atomicAdd(&s[r], norm);
    int idx = lane * 4;
    int b = idx >> 7;
    int f = idx & 127;
    float4 v = *(const float4*)(x + (size_t)b * NF + (size_t)c * F + f);
    float* dst = out + (size_t)b * NF + (size_t)r * F + f;
    atomicAdd(dst + 0, norm * v.x);
    atomicAdd(dst + 1, norm * v.y);
    atomicAdd(dst + 2, norm * v.z);
    atomicAdd(dst + 3, norm * v.w);
}
__global__ void k_self(const float* __restrict__ x, const float* __restrict__ dinv,
                       float* __restrict__ out) {
    int i = blockIdx.x * 256 + threadIdx.x;
    if (i >= 2 * NF / 4) return;
    size_t base = (size_t)i * 4;
    int b = (base >= (size_t)NF) ? 1 : 0;
    size_t rem = base - (size_t)b * NF;
    int n = (int)(rem >> 7);
    float dn = dinv[n]; float sc = dn * dn;
    float4 v = *(const float4*)(x + base);
    float4* op = (float4*)(out + base);
    float4 o = *op;
    o.x += sc * v.x; o.y += sc * v.y; o.z += sc * v.z; o.w += sc * v.w;
    *op = o;
}
__global__ void k_sfix(const float* __restrict__ dinv, float* __restrict__ s) {
    int n = blockIdx.x * 256 + threadIdx.x;
    if (n < N_NODES) { float dn = dinv[n]; s[n] += dn * dn; }
}

// ========== MFMA GEMM from fp32 out via LDS (fallback) ======================
__global__ __launch_bounds__(256) void k_gemm1(const float* __restrict__ W,
                                               const float* __restrict__ bias,
                                               const float* __restrict__ s,
                                               float* __restrict__ out) {
    __shared__ _Float16 sW[128 * 136];
    __shared__ _Float16 sA[64 * 136];
    const int tid = threadIdx.x;
    const int b   = blockIdx.y;
    const int n0  = blockIdx.x * 64;
    float* ob = out + (size_t)b * NF;

    for (int i = 0; i < 16; ++i) {
        int idx = (i * 256 + tid) * 4;
        int o = idx >> 7, k = idx & 127;
        float4 w = *(const float4*)(W + idx);
        half4 h;
        h[0] = (_Float16)w.x; h[1] = (_Float16)w.y;
        h[2] = (_Float16)w.z; h[3] = (_Float16)w.w;
        *(half4*)&sW[o * 136 + k] = h;
    }
    for (int i = 0; i < 8; ++i) {
        int idx = (i * 256 + tid) * 4;
        int nl = idx >> 7, k = idx & 127;
        int n = n0 + nl;
        half4 h = {(_Float16)0.f, (_Float16)0.f, (_Float16)0.f, (_Float16)0.f};
        if (n < N_NODES) {
            float4 v = *(const float4*)(ob + (size_t)n * F + k);
            h[0] = (_Float16)v.x; h[1] = (_Float16)v.y;
            h[2] = (_Float16)v.z; h[3] = (_Float16)v.w;
        }
        *(half4*)&sA[nl * 136 + k] = h;
    }
    __syncthreads();

    const int wave = tid >> 6, lane = tid & 63;
    const int ln = lane & 15, quad = lane >> 4;
    const int nw = wave * 16;
    if (n0 + nw >= N_NODES) return;

    floatx4 acc[8];
    for (int ot = 0; ot < 8; ++ot) acc[ot] = (floatx4){0.f, 0.f, 0.f, 0.f};

    for (int k0 = 0; k0 < 4; ++k0) {
        half8 a = *(const half8*)&sA[(nw + ln) * 136 + k0 * 32 + quad * 8];
        for (int ot = 0; ot < 8; ++ot) {
            half8 bf = *(const half8*)&sW[(ot * 16 + ln) * 136 + k0 * 32 + quad * 8];
            acc[ot] = __builtin_amdgcn_mfma_f32_16x16x32_f16(a, bf, acc[ot], 0, 0, 0);
        }
    }

    float sv[4];
    for (int rg = 0; rg < 4; ++rg) sv[rg] = s[n0 + nw + quad * 4 + rg];
    for (int ot = 0; ot < 8; ++ot) {
        int o = ot * 16 + ln;
        float bo = bias[o];
        for (int rg = 0; rg < 4; ++rg) {
            int n = n0 + nw + quad * 4 + rg;
            float v = acc[ot][rg] + sv[rg] * bo;
            ob[(size_t)n * F + o] = fmaxf(v, 0.0f);
        }
    }
}

extern "C" void kernel_launch(void* const* d_in, const int* in_sizes, int n_in,
                              void* d_out, int out_size, void* d_ws, size_t ws_size,
                              hipStream_t stream) {
    const float* x    = (const float*)d_in[0];
    const int*   ei   = (const int*)d_in[1];
    const float* attr = (const float*)d_in[2];
    const float* W    = (const float*)d_in[3];
    const float* bias = (const float*)d_in[4];
    float* out = (float*)d_out;

    // ws layout: cnt[N+1] | dinv[N] (deg during scatter) | s[N] | pad16 |
    //            spill[SPILL_CAP]*16B | slots[N*CAP]*4B | xi[2NF]*2B | Wh[128*128]*2B
    int*   cnt  = (int*)d_ws;
    float* dinv = (float*)(cnt + N_NODES + 1);   // deg during scatter; fallback: deg
    float* s    = dinv + N_NODES;
    size_t spill_off = ((size_t)((char*)(s + N_NODES) - (char*)d_ws) + 15) & ~(size_t)15;
    uint4* spill = (uint4*)((char*)d_ws + spill_off);
    size_t slots_off = spill_off + (size_t)SPILL_CAP * 16;
    unsigned* slots = (unsigned*)((char*)d_ws + slots_off);
    size_t xi_off = slots_off + (size_t)N_NODES * CAP * 4;
    _Float16* xi = (_Float16*)((char*)d_ws + xi_off);
    size_t wh_off = xi_off + (size_t)2 * NF * 2;
    _Float16* Wh = (_Float16*)((char*)d_ws + wh_off);
    size_t need_F = wh_off + (size_t)128 * 128 * 2;

    if (ws_size >= need_F) {
        // zero cnt[N+1] + deg[N] (contiguous)
        hipMemsetAsync(cnt, 0, (size_t)(2 * N_NODES + 1) * sizeof(int), stream);
        k_scatter<<<782, 256, 0, stream>>>(ei, attr, cnt, dinv, spill, slots);
        k_prep<<<12500, 256, 0, stream>>>(x, W, dinv, xi, Wh);
        k_fused<<<N_NODES / TILE, 256, 0, stream>>>(cnt, slots, spill, xi, dinv, Wh, bias, out);
    } else {
        // atomic fallback: needs deg/dinv[N]+s[N] only
        hipMemsetAsync(dinv, 0, N_NODES * sizeof(float), stream);
        hipMemsetAsync(s, 0, N_NODES * sizeof(float), stream);
        hipMemsetAsync(out, 0, (size_t)2 * NF * sizeof(float), stream);
        k_deg<<<(N_EDGES + 255) / 256, 256, 0, stream>>>(ei, attr, dinv);
        k_dinv<<<(N_NODES + 255) / 256, 256, 0, stream>>>(dinv);
        size_t edge_threads = (size_t)N_EDGES * 64;
        k_edge<<<(unsigned)((edge_threads + 255) / 256), 256, 0, stream>>>(
            ei, attr, dinv, x, out, s);
        k_self<<<(2 * NF / 4 + 255) / 256, 256, 0, stream>>>(x, dinv, out);
        k_sfix<<<(N_NODES + 255) / 256, 256, 0, stream>>>(dinv, s);
        dim3 gg((N_NODES + 63) / 64, 2);
        k_gemm1<<<gg, 256, 0, stream>>>(W, bias, s, out);
    }
}

// Round 7
// 230.835 us; speedup vs baseline: 1.6548x; 1.6548x over previous
//
#include <hip/hip_runtime.h>

#define N_NODES 50000
#define N_EDGES 800000
#define F 128
#define BF 256
#define NF (N_NODES * F)
#define CAP 64                       // slots per node (max degree here ~40)
#define SPILL_CAP 131072
#define TILE 16
#define AGS 264                      // LDS row stride in halfs: 528B, 16B-aligned
#define Q14 16383.0f                 // deg-sum quantization (20-bit field)
#define Q15 32767.0f                 // slot weight quantization

typedef __attribute__((ext_vector_type(8))) _Float16 half8;
typedef __attribute__((ext_vector_type(4))) _Float16 half4;
typedef __attribute__((ext_vector_type(4))) float floatx4;

#define RL_I(v, l) __builtin_amdgcn_readlane((v), (l))

// ========== scatter: 4-edge batched, ONE packed atomic per edge =============
// cnt[r] accumulates (count << 20) | sum(q14(attr)): slot index AND weighted
// degree in a single fabric atomic. sum <= 64*16383 < 2^20 (max degree ~40).
__global__ __launch_bounds__(256) void k_scatter(const int* __restrict__ ei,
                                                 const float* __restrict__ attr,
                                                 unsigned* __restrict__ cnt,   // [N+1], last = nspill
                                                 uint4* __restrict__ spill,
                                                 unsigned* __restrict__ slots) // [N][CAP] c<<15|q15(a)
{
    int t = blockIdx.x * 256 + threadIdx.x;
    if (t >= 200000) return;                  // 200000 * 4 == N_EDGES
    int e0 = t, e1 = t + 200000, e2 = t + 400000, e3 = t + 600000;
    int   r0 = ei[e0], r1 = ei[e1], r2 = ei[e2], r3 = ei[e3];
    int   c0 = ei[N_EDGES + e0], c1 = ei[N_EDGES + e1];
    int   c2 = ei[N_EDGES + e2], c3 = ei[N_EDGES + e3];
    float a0 = attr[e0], a1 = attr[e1], a2 = attr[e2], a3 = attr[e3];

    unsigned p0 = (1u << 20) | (unsigned)(a0 * Q14 + 0.5f);
    unsigned p1 = (1u << 20) | (unsigned)(a1 * Q14 + 0.5f);
    unsigned p2 = (1u << 20) | (unsigned)(a2 * Q14 + 0.5f);
    unsigned p3 = (1u << 20) | (unsigned)(a3 * Q14 + 0.5f);

    int s0 = (int)(atomicAdd(&cnt[r0], p0) >> 20);
    int s1 = (int)(atomicAdd(&cnt[r1], p1) >> 20);
    int s2 = (int)(atomicAdd(&cnt[r2], p2) >> 20);
    int s3 = (int)(atomicAdd(&cnt[r3], p3) >> 20);

#define STORE_EDGE(R, C, A, S)                                                \
    {                                                                         \
        unsigned q  = (unsigned)((A) * Q15 + 0.5f);                           \
        unsigned pk = ((unsigned)(C) << 15) | q;                              \
        if ((S) < CAP) {                                                      \
            slots[(size_t)(R) * CAP + (S)] = pk;                              \
        } else {                                                              \
            int sp = (int)atomicAdd(&cnt[N_NODES], 1u);                       \
            if (sp < SPILL_CAP)                                               \
                spill[sp] = make_uint4((unsigned)(R), (unsigned)(C),          \
                                       __float_as_uint(A), 0u);               \
        }                                                                     \
    }
    STORE_EDGE(r0, c0, a0, s0)
    STORE_EDGE(r1, c1, a1, s1)
    STORE_EDGE(r2, c2, a2, s2)
    STORE_EDGE(r3, c3, a3, s3)
#undef STORE_EDGE
}

// ========== prep: pure streaming — x->fp16, W->fp16, dinv from packed cnt ===
__global__ __launch_bounds__(256) void k_prep(const unsigned* __restrict__ cnt,
                                              const float* __restrict__ x,
                                              const float* __restrict__ W,
                                              float* __restrict__ dinv,
                                              _Float16* __restrict__ xi,
                                              _Float16* __restrict__ Wh) {
    int t = blockIdx.x * 256 + threadIdx.x;   // 12500 blocks * 256 == 2*NF/4

    {
        size_t base = (size_t)t * 4;
        int b = (base >= (size_t)NF) ? 1 : 0;
        size_t rem = base - (size_t)b * NF;
        int n = (int)(rem >> 7);
        int f = (int)(rem & 127);
        float4 v = *(const float4*)(x + base);
        half4 h;
        h[0] = (_Float16)v.x; h[1] = (_Float16)v.y;
        h[2] = (_Float16)v.z; h[3] = (_Float16)v.w;
        *(half4*)(xi + (size_t)n * BF + b * F + f) = h;
    }
    if (t < 4096) {
        float4 w = ((const float4*)W)[t];
        half4 h;
        h[0] = (_Float16)w.x; h[1] = (_Float16)w.y;
        h[2] = (_Float16)w.z; h[3] = (_Float16)w.w;
        ((half4*)Wh)[t] = h;
    }
    if (t < N_NODES) {
        float dsum = (float)(cnt[t] & 0xFFFFFu) * (1.0f / Q14);
        dinv[t] = rsqrtf(dsum + 1.0f);
    }
}

// Unrolled neighbor accumulation: 8 independent wave-wide 512B loads in flight.
#define NB_ONE(CJ, PJ)                                                        \
    {                                                                         \
        half4 v = *(const half4*)(xi + (size_t)(CJ) * BF + idx);              \
        acc.x += (PJ) * (float)v[0]; acc.y += (PJ) * (float)v[1];             \
        acc.z += (PJ) * (float)v[2]; acc.w += (PJ) * (float)v[3];             \
        sp += (PJ);                                                           \
    }

#define NB_BODY                                                               \
    float4 acc  = make_float4(0.f, 0.f, 0.f, 0.f);                            \
    float4 accB = make_float4(0.f, 0.f, 0.f, 0.f);                            \
    float sp = 0.0f;                                                          \
    int pwi = __float_as_int(pw);                                             \
    int j = 0;                                                                \
    for (; j + 8 <= m; j += 8) {                                              \
        int c0 = RL_I(ec, j + 0), c1 = RL_I(ec, j + 1);                       \
        int c2 = RL_I(ec, j + 2), c3 = RL_I(ec, j + 3);                       \
        int c4 = RL_I(ec, j + 4), c5 = RL_I(ec, j + 5);                       \
        int c6 = RL_I(ec, j + 6), c7 = RL_I(ec, j + 7);                       \
        float p0 = __int_as_float(RL_I(pwi, j + 0));                          \
        float p1 = __int_as_float(RL_I(pwi, j + 1));                          \
        float p2 = __int_as_float(RL_I(pwi, j + 2));                          \
        float p3 = __int_as_float(RL_I(pwi, j + 3));                          \
        float p4 = __int_as_float(RL_I(pwi, j + 4));                          \
        float p5 = __int_as_float(RL_I(pwi, j + 5));                          \
        float p6 = __int_as_float(RL_I(pwi, j + 6));                          \
        float p7 = __int_as_float(RL_I(pwi, j + 7));                          \
        half4 v0 = *(const half4*)(xi + (size_t)c0 * BF + idx);               \
        half4 v1 = *(const half4*)(xi + (size_t)c1 * BF + idx);               \
        half4 v2 = *(const half4*)(xi + (size_t)c2 * BF + idx);               \
        half4 v3 = *(const half4*)(xi + (size_t)c3 * BF + idx);               \
        half4 v4 = *(const half4*)(xi + (size_t)c4 * BF + idx);               \
        half4 v5 = *(const half4*)(xi + (size_t)c5 * BF + idx);               \
        half4 v6 = *(const half4*)(xi + (size_t)c6 * BF + idx);               \
        half4 v7 = *(const half4*)(xi + (size_t)c7 * BF + idx);               \
        acc.x  += p0 * (float)v0[0]; acc.y  += p0 * (float)v0[1];             \
        acc.z  += p0 * (float)v0[2]; acc.w  += p0 * (float)v0[3];             \
        accB.x += p1 * (float)v1[0]; accB.y += p1 * (float)v1[1];             \
        accB.z += p1 * (float)v1[2]; accB.w += p1 * (float)v1[3];             \
        acc.x  += p2 * (float)v2[0]; acc.y  += p2 * (float)v2[1];             \
        acc.z  += p2 * (float)v2[2]; acc.w  += p2 * (float)v2[3];             \
        accB.x += p3 * (float)v3[0]; accB.y += p3 * (float)v3[1];             \
        accB.z += p3 * (float)v3[2]; accB.w += p3 * (float)v3[3];             \
        acc.x  += p4 * (float)v4[0]; acc.y  += p4 * (float)v4[1];             \
        acc.z  += p4 * (float)v4[2]; acc.w  += p4 * (float)v4[3];             \
        accB.x += p5 * (float)v5[0]; accB.y += p5 * (float)v5[1];             \
        accB.z += p5 * (float)v5[2]; accB.w += p5 * (float)v5[3];             \
        acc.x  += p6 * (float)v6[0]; acc.y  += p6 * (float)v6[1];             \
        acc.z  += p6 * (float)v6[2]; acc.w  += p6 * (float)v6[3];             \
        accB.x += p7 * (float)v7[0]; accB.y += p7 * (float)v7[1];             \
        accB.z += p7 * (float)v7[2]; accB.w += p7 * (float)v7[3];             \
        sp += p0 + p1 + p2 + p3 + p4 + p5 + p6 + p7;                          \
    }                                                                         \
    if (j + 4 <= m) {                                                         \
        int c0 = RL_I(ec, j + 0), c1 = RL_I(ec, j + 1);                       \
        int c2 = RL_I(ec, j + 2), c3 = RL_I(ec, j + 3);                       \
        float p0 = __int_as_float(RL_I(pwi, j + 0));                          \
        float p1 = __int_as_float(RL_I(pwi, j + 1));                          \
        float p2 = __int_as_float(RL_I(pwi, j + 2));                          \
        float p3 = __int_as_float(RL_I(pwi, j + 3));                          \
        half4 v0 = *(const half4*)(xi + (size_t)c0 * BF + idx);               \
        half4 v1 = *(const half4*)(xi + (size_t)c1 * BF + idx);               \
        half4 v2 = *(const half4*)(xi + (size_t)c2 * BF + idx);               \
        half4 v3 = *(const half4*)(xi + (size_t)c3 * BF + idx);               \
        acc.x  += p0 * (float)v0[0]; acc.y  += p0 * (float)v0[1];             \
        acc.z  += p0 * (float)v0[2]; acc.w  += p0 * (float)v0[3];             \
        accB.x += p1 * (float)v1[0]; accB.y += p1 * (float)v1[1];             \
        accB.z += p1 * (float)v1[2]; accB.w += p1 * (float)v1[3];             \
        acc.x  += p2 * (float)v2[0]; acc.y  += p2 * (float)v2[1];             \
        acc.z  += p2 * (float)v2[2]; acc.w  += p2 * (float)v2[3];             \
        accB.x += p3 * (float)v3[0]; accB.y += p3 * (float)v3[1];             \
        accB.z += p3 * (float)v3[2]; accB.w += p3 * (float)v3[3];             \
        sp += p0 + p1 + p2 + p3;                                              \
        j += 4;                                                               \
    }                                                                         \
    for (; j < m; ++j) {                                                      \
        int   c = RL_I(ec, j);                                                \
        float p = __int_as_float(RL_I(pwi, j));                               \
        NB_ONE(c, p)                                                          \
    }                                                                         \
    acc.x += accB.x; acc.y += accB.y; acc.z += accB.z; acc.w += accB.w;

// ========== fused gather (LDS tile) + MFMA GEMM, row-pipelined ==============
__global__ __launch_bounds__(256, 8) void k_fused(const unsigned* __restrict__ cnt,
                                                  const unsigned* __restrict__ slots,
                                                  const uint4* __restrict__ spill,
                                                  const _Float16* __restrict__ xi,
                                                  const float* __restrict__ dinv,
                                                  const _Float16* __restrict__ Wh,
                                                  const float* __restrict__ bias,
                                                  float* __restrict__ out) {
    __shared__ _Float16 ag[TILE * AGS];
    __shared__ float ss[TILE];
    const int tid  = threadIdx.x;
    const int wave = tid >> 6, lane = tid & 63;
    const int n0   = blockIdx.x * TILE;           // 3125*16 == 50000 exactly
    const int idx  = lane * 4;
    const int rbase = n0 + wave * 4;

    // ---- gather phase: 4 rows per wave, 2-stage software pipeline ----
    int cns[4];
#pragma unroll
    for (int i = 0; i < 4; ++i) cns[i] = (int)(cnt[rbase + i] >> 20);

    // prefetch row 0 meta
    unsigned pk_cur = 0u;
    float    dp_cur = 0.0f;
    {
        int m0 = (cns[0] < CAP) ? cns[0] : CAP;
        if (lane < m0) {
            pk_cur = slots[(size_t)rbase * CAP + lane];
            dp_cur = dinv[pk_cur >> 15];
        }
    }

#pragma unroll
    for (int i = 0; i < 4; ++i) {
        const int rl = wave * 4 + i;
        const int r  = rbase + i;
        const int cn = cns[i];
        const int m  = (cn < CAP) ? cn : CAP;

        int   ec = (int)(pk_cur >> 15);
        float pw = (lane < m) ? (float)(pk_cur & 0x7FFFu) * (1.0f / Q15) * dp_cur : 0.0f;

        // prefetch next row meta; latency hides under this row's NB loop
        unsigned pk_nxt = 0u;
        float    dp_nxt = 0.0f;
        if (i < 3) {
            int mn = (cns[i + 1] < CAP) ? cns[i + 1] : CAP;
            if (lane < mn) {
                pk_nxt = slots[(size_t)(r + 1) * CAP + lane];
                dp_nxt = dinv[pk_nxt >> 15];
            }
        }

        float dinvr = dinv[r];
        float nm0   = dinvr * dinvr;
        half4 hv    = *(const half4*)(xi + (size_t)r * BF + idx);

        NB_BODY

        if (cn > CAP) {
            int ns = (int)cnt[N_NODES]; if (ns > SPILL_CAP) ns = SPILL_CAP;
            for (int k = 0; k < ns; ++k) {
                uint4 e = spill[k];
                if ((int)e.x == r) {
                    int c = (int)e.y;
                    float p = __uint_as_float(e.z) * dinv[c];
                    NB_ONE(c, p)
                }
            }
        }

        half4 ho;
        ho[0] = (_Float16)(dinvr * acc.x + nm0 * (float)hv[0]);
        ho[1] = (_Float16)(dinvr * acc.y + nm0 * (float)hv[1]);
        ho[2] = (_Float16)(dinvr * acc.z + nm0 * (float)hv[2]);
        ho[3] = (_Float16)(dinvr * acc.w + nm0 * (float)hv[3]);
        *(half4*)&ag[rl * AGS + idx] = ho;
        if (lane == 0) ss[rl] = dinvr * sp + nm0;

        pk_cur = pk_nxt;
        dp_cur = dp_nxt;
    }
    __syncthreads();

    // ---- GEMM phase: wave handles output cols [wave*32, wave*32+32) ----
    const int ln = lane & 15, quad = lane >> 4;
    const int obase = wave * 32;
    floatx4 acc00 = (floatx4){0.f,0.f,0.f,0.f}, acc01 = acc00;
    floatx4 acc10 = acc00, acc11 = acc00;

    for (int k0 = 0; k0 < 4; ++k0) {
        half8 a0 = *(const half8*)&ag[ln * AGS + k0 * 32 + quad * 8];        // batch 0
        half8 a1 = *(const half8*)&ag[ln * AGS + 128 + k0 * 32 + quad * 8];  // batch 1
        half8 b0 = *(const half8*)(Wh + (size_t)(obase + ln) * F + k0 * 32 + quad * 8);
        half8 b1 = *(const half8*)(Wh + (size_t)(obase + 16 + ln) * F + k0 * 32 + quad * 8);
        acc00 = __builtin_amdgcn_mfma_f32_16x16x32_f16(a0, b0, acc00, 0, 0, 0);
        acc01 = __builtin_amdgcn_mfma_f32_16x16x32_f16(a0, b1, acc01, 0, 0, 0);
        acc10 = __builtin_amdgcn_mfma_f32_16x16x32_f16(a1, b0, acc10, 0, 0, 0);
        acc11 = __builtin_amdgcn_mfma_f32_16x16x32_f16(a1, b1, acc11, 0, 0, 0);
    }

    float sv[4];
    for (int rg = 0; rg < 4; ++rg) sv[rg] = ss[quad * 4 + rg];
    {
        int o0 = obase + ln, o1 = obase + 16 + ln;
        float bo0 = bias[o0], bo1 = bias[o1];
        for (int rg = 0; rg < 4; ++rg) {
            int n = n0 + quad * 4 + rg;
            out[(size_t)n * F + o0]              = fmaxf(acc00[rg] + sv[rg] * bo0, 0.0f);
            out[(size_t)n * F + o1]              = fmaxf(acc01[rg] + sv[rg] * bo1, 0.0f);
            out[(size_t)NF + (size_t)n * F + o0] = fmaxf(acc10[rg] + sv[rg] * bo0, 0.0f);
            out[(size_t)NF + (size_t)n * F + o1] = fmaxf(acc11[rg] + sv[rg] * bo1, 0.0f);
        }
    }
}

// ========== atomic fallback pieces (tiny ws) ================================
__global__ void k_deg(const int* __restrict__ ei, const float* __restrict__ attr,
                      float* __restrict__ deg) {
    int e = blockIdx.x * 256 + threadIdx.x;
    if (e < N_EDGES) atomicAdd(&deg[ei[e]], attr[e]);
}
__global__ void k_dinv(float* __restrict__ deg) {
    int n = blockIdx.x * 256 + threadIdx.x;
    if (n < N_NODES) deg[n] = rsqrtf(deg[n] + 1.0f);
}
__global__ __launch_bounds__(256) void k_edge(const int* __restrict__ ei,
                                              const float* __restrict__ attr,
                                              const float* __restrict__ dinv,
                                              const float* __restrict__ x,
                                              float* __restrict__ out,
                                              float* __restrict__ s) {
    int e    = (int)(((size_t)blockIdx.x * 256 + threadIdx.x) >> 6);
    int lane = threadIdx.x & 63;
    if (e >= N_EDGES) return;
    int r = ei[e];
    int c = ei[N_EDGES + e];
    float norm = dinv[r] * attr[e] * dinv[c];
    if (lane == 0) atomicAdd(&s[r], norm);
    int idx = lane * 4;
    int b = idx >> 7;
    int f = idx & 127;
    float4 v = *(const float4*)(x + (size_t)b * NF + (size_t)c * F + f);
    float* dst = out + (size_t)b * NF + (size_t)r * F + f;
    atomicAdd(dst + 0, norm * v.x);
    atomicAdd(dst + 1, norm * v.y);
    atomicAdd(dst + 2, norm * v.z);
    atomicAdd(dst + 3, norm * v.w);
}
__global__ void k_self(const float* __restrict__ x, const float* __restrict__ dinv,
                       float* __restrict__ out) {
    int i = blockIdx.x * 256 + threadIdx.x;
    if (i >= 2 * NF / 4) return;
    size_t base = (size_t)i * 4;
    int b = (base >= (size_t)NF) ? 1 : 0;
    size_t rem = base - (size_t)b * NF;
    int n = (int)(rem >> 7);
    float dn = dinv[n]; float sc = dn * dn;
    float4 v = *(const float4*)(x + base);
    float4* op = (float4*)(out + base);
    float4 o = *op;
    o.x += sc * v.x; o.y += sc * v.y; o.z += sc * v.z; o.w += sc * v.w;
    *op = o;
}
__global__ void k_sfix(const float* __restrict__ dinv, float* __restrict__ s) {
    int n = blockIdx.x * 256 + threadIdx.x;
    if (n < N_NODES) { float dn = dinv[n]; s[n] += dn * dn; }
}

// ========== MFMA GEMM from fp32 out via LDS (fallback) ======================
__global__ __launch_bounds__(256) void k_gemm1(const float* __restrict__ W,
                                               const float* __restrict__ bias,
                                               const float* __restrict__ s,
                                               float* __restrict__ out) {
    __shared__ _Float16 sW[128 * 136];
    __shared__ _Float16 sA[64 * 136];
    const int tid = threadIdx.x;
    const int b   = blockIdx.y;
    const int n0  = blockIdx.x * 64;
    float* ob = out + (size_t)b * NF;

    for (int i = 0; i < 16; ++i) {
        int idx = (i * 256 + tid) * 4;
        int o = idx >> 7, k = idx & 127;
        float4 w = *(const float4*)(W + idx);
        half4 h;
        h[0] = (_Float16)w.x; h[1] = (_Float16)w.y;
        h[2] = (_Float16)w.z; h[3] = (_Float16)w.w;
        *(half4*)&sW[o * 136 + k] = h;
    }
    for (int i = 0; i < 8; ++i) {
        int idx = (i * 256 + tid) * 4;
        int nl = idx >> 7, k = idx & 127;
        int n = n0 + nl;
        half4 h = {(_Float16)0.f, (_Float16)0.f, (_Float16)0.f, (_Float16)0.f};
        if (n < N_NODES) {
            float4 v = *(const float4*)(ob + (size_t)n * F + k);
            h[0] = (_Float16)v.x; h[1] = (_Float16)v.y;
            h[2] = (_Float16)v.z; h[3] = (_Float16)v.w;
        }
        *(half4*)&sA[nl * 136 + k] = h;
    }
    __syncthreads();

    const int wave = tid >> 6, lane = tid & 63;
    const int ln = lane & 15, quad = lane >> 4;
    const int nw = wave * 16;
    if (n0 + nw >= N_NODES) return;

    floatx4 acc[8];
    for (int ot = 0; ot < 8; ++ot) acc[ot] = (floatx4){0.f, 0.f, 0.f, 0.f};

    for (int k0 = 0; k0 < 4; ++k0) {
        half8 a = *(const half8*)&sA[(nw + ln) * 136 + k0 * 32 + quad * 8];
        for (int ot = 0; ot < 8; ++ot) {
            half8 bf = *(const half8*)&sW[(ot * 16 + ln) * 136 + k0 * 32 + quad * 8];
            acc[ot] = __builtin_amdgcn_mfma_f32_16x16x32_f16(a, bf, acc[ot], 0, 0, 0);
        }
    }

    float sv[4];
    for (int rg = 0; rg < 4; ++rg) sv[rg] = s[n0 + nw + quad * 4 + rg];
    for (int ot = 0; ot < 8; ++ot) {
        int o = ot * 16 + ln;
        float bo = bias[o];
        for (int rg = 0; rg < 4; ++rg) {
            int n = n0 + nw + quad * 4 + rg;
            float v = acc[ot][rg] + sv[rg] * bo;
            ob[(size_t)n * F + o] = fmaxf(v, 0.0f);
        }
    }
}

extern "C" void kernel_launch(void* const* d_in, const int* in_sizes, int n_in,
                              void* d_out, int out_size, void* d_ws, size_t ws_size,
                              hipStream_t stream) {
    const float* x    = (const float*)d_in[0];
    const int*   ei   = (const int*)d_in[1];
    const float* attr = (const float*)d_in[2];
    const float* W    = (const float*)d_in[3];
    const float* bias = (const float*)d_in[4];
    float* out = (float*)d_out;

    // ws layout: cnt[N+1] | dinv[N] | s[N] | pad16 |
    //            spill[SPILL_CAP]*16B | slots[N*CAP]*4B | xi[2NF]*2B | Wh[128*128]*2B
    unsigned* cnt  = (unsigned*)d_ws;
    float*    dinv = (float*)(cnt + N_NODES + 1);   // fallback: deg
    float*    s    = dinv + N_NODES;
    size_t spill_off = ((size_t)((char*)(s + N_NODES) - (char*)d_ws) + 15) & ~(size_t)15;
    uint4* spill = (uint4*)((char*)d_ws + spill_off);
    size_t slots_off = spill_off + (size_t)SPILL_CAP * 16;
    unsigned* slots = (unsigned*)((char*)d_ws + slots_off);
    size_t xi_off = slots_off + (size_t)N_NODES * CAP * 4;
    _Float16* xi = (_Float16*)((char*)d_ws + xi_off);
    size_t wh_off = xi_off + (size_t)2 * NF * 2;
    _Float16* Wh = (_Float16*)((char*)d_ws + wh_off);
    size_t need_F = wh_off + (size_t)128 * 128 * 2;

    if (ws_size >= need_F) {
        hipMemsetAsync(cnt, 0, (N_NODES + 1) * sizeof(unsigned), stream);
        k_scatter<<<782, 256, 0, stream>>>(ei, attr, cnt, spill, slots);
        k_prep<<<12500, 256, 0, stream>>>(cnt, x, W, dinv, xi, Wh);
        k_fused<<<N_NODES / TILE, 256, 0, stream>>>(cnt, slots, spill, xi, dinv, Wh, bias, out);
    } else {
        // atomic fallback: needs deg/dinv[N]+s[N] only
        hipMemsetAsync(dinv, 0, N_NODES * sizeof(float), stream);
        hipMemsetAsync(s, 0, N_NODES * sizeof(float), stream);
        hipMemsetAsync(out, 0, (size_t)2 * NF * sizeof(float), stream);
        k_deg<<<(N_EDGES + 255) / 256, 256, 0, stream>>>(ei, attr, dinv);
        k_dinv<<<(N_NODES + 255) / 256, 256, 0, stream>>>(dinv);
        size_t edge_threads = (size_t)N_EDGES * 64;
        k_edge<<<(unsigned)((edge_threads + 255) / 256), 256, 0, stream>>>(
            ei, attr, dinv, x, out, s);
        k_self<<<(2 * NF / 4 + 255) / 256, 256, 0, stream>>>(x, dinv, out);
        k_sfix<<<(N_NODES + 255) / 256, 256, 0, stream>>>(dinv, s);
        dim3 gg((N_NODES + 63) / 64, 2);
        k_gemm1<<<gg, 256, 0, stream>>>(W, bias, s, out);
    }
}